// Round 7
// baseline (254.563 us; speedup 1.0000x reference)
//
#include <hip/hip_runtime.h>
#include <hip/hip_bf16.h>
#include <stdint.h>

#define BATCH 512
#define NN 32
#define T_IN 12
#define HID 64
#define HEADS 8
#define OUT_CH 9
#define EPB (NN*8)       // 256 edges per batch (before self loops)
#define ETOT (EPB+NN)    // 288 with self loops
#define F1 (HEADS*HID)   // 512

using u16 = unsigned short;
using u32 = unsigned int;
typedef _Float16 f16;
typedef _Float16 f16x2 __attribute__((ext_vector_type(2)));
typedef u32 v4u __attribute__((ext_vector_type(4)));
typedef float v4f __attribute__((ext_vector_type(4)));

__device__ __forceinline__ float bf2f(u16 u){ return __uint_as_float(((u32)u)<<16); }
__device__ __forceinline__ u16 f2bf(float f){
    u32 x = __float_as_uint(f);
    u32 r = (x + 0x7FFFu + ((x>>16)&1u))>>16;
    return (u16)r;
}
__device__ __forceinline__ u32 packf16(float a, float b){
    f16x2 p; p.x=(f16)a; p.y=(f16)b; return __builtin_bit_cast(u32,p);
}
__device__ __forceinline__ u16 f2h16(float a){ f16 h=(f16)a; return __builtin_bit_cast(u16,h); }
__device__ __forceinline__ float lof(u32 w){ return (float)__builtin_bit_cast(f16x2,w).x; }
__device__ __forceinline__ float hif(u32 w){ return (float)__builtin_bit_cast(f16x2,w).y; }
__device__ __forceinline__ float dot2(u32 a, u32 b, float c){
#if __has_builtin(__builtin_amdgcn_fdot2)
    return __builtin_amdgcn_fdot2(__builtin_bit_cast(f16x2,a), __builtin_bit_cast(f16x2,b), c, false);
#else
    return fmaf(lof(a),lof(b), fmaf(hif(a),hif(b), c));
#endif
}
__device__ __forceinline__ float elu1(float x){ return x > 0.f ? x : (__expf(x)-1.f); }
__device__ __forceinline__ float sigm(float x){ return 1.f/(1.f+__expf(-x)); }
__device__ __forceinline__ float tanh_(float x){ return 1.f - 2.f/(__expf(2.f*x)+1.f); }
__device__ __forceinline__ u32 fenc(float v){
    u32 b=__float_as_uint(v);
    return (b&0x80000000u) ? ~b : (b|0x80000000u);
}
__device__ __forceinline__ float fdec(u32 k){
    return __uint_as_float((k&0x80000000u) ? (k&0x7FFFFFFFu) : ~k);
}

#define DOT4(acc,A,W) do{ acc=dot2(A.x,W.x,acc); acc=dot2(A.y,W.y,acc); \
                          acc=dot2(A.z,W.z,acc); acc=dot2(A.w,W.w,acc); }while(0)

// ------------------------------------------------ canonicalize inputs into ws (fp32)
struct CvtDesc {
    const void* src[16];
    void*       dst[16];
    int         n[16];
};

// merged detect + convert + W2 interleave + GRU weight packing (one launch).
__global__ __launch_bounds__(256) void k_setup(
    const u32* __restrict__ xw, CvtDesc d,
    const void* __restrict__ W2src, u16* __restrict__ W2i,
    const void* __restrict__ Wi1, const void* __restrict__ Wh1,
    const void* __restrict__ Wi2, const void* __restrict__ Wh2,
    u32* __restrict__ wpk, int* __restrict__ flag)
{
    __shared__ int cnt;
    if(threadIdx.x==0) cnt=0;
    __syncthreads();
    int c=0;
    for(int i=threadIdx.x;i<4096;i+=256){
        u32 w=xw[i];
        if(w & 0x7FFFFFFFu){
            u32 el=(w>>7)&0xFFu;
            if(el>=0x90u) c++;
        }
    }
    atomicAdd(&cnt,c);
    __syncthreads();
    const int f = (cnt>256) ? 1 : 0;   // 1 = fp32 inputs, 0 = bf16
    if(blockIdx.x==0 && threadIdx.x==0) *flag=f;

    const int bk=blockIdx.x;
    if(bk<128){
        int seg=bk>>3, sub=bk&7;
        const void* s=d.src[seg];
        float* o=(float*)d.dst[seg];
        int n=d.n[seg];
        for(int i=sub*256+threadIdx.x;i<n;i+=2048)
            o[i] = f ? ((const float*)s)[i] : bf2f(((const u16*)s)[i]);
    } else if(bk<256){
        // W2 [512][64] -> interleaved fp16 W2i[(k>>3)*64+j][k&7]
        int i=(bk-128)*256+threadIdx.x;
        int k=i>>6, j=i&63;
        float v = f? ((const float*)W2src)[i] : bf2f(((const u16*)W2src)[i]);
        W2i[ (((size_t)(k>>3)*64 + j)<<3) + (k&7) ] = f2h16(v);
    } else {
        // GRU weights -> packed fp16 [4][192 rows][32 u32] (K=64, Wi1 zero-padded)
        int w=(bk-256)*256+threadIdx.x;
        int m=w/6144;
        int rem=w-m*6144;
        int row=rem>>5, kw=rem&31;
        const void* s=(m==0)?Wi1:(m==1)?Wh1:(m==2)?Wi2:Wh2;
        int K=(m==0)?32:64;
        int k0=2*kw, k1=k0+1;
        float v0=0.f, v1=0.f;
        if(k0<K) v0 = f? ((const float*)s)[row*K+k0] : bf2f(((const u16*)s)[row*K+k0]);
        if(k1<K) v1 = f? ((const float*)s)[row*K+k1] : bf2f(((const u16*)s)[row*K+k1]);
        wpk[w]=packf16(v0,v1);
    }
}

// =====================================================================
// FUSED kernel, 512 threads / 8 waves.
// Round-6 diagnosis: at 256 threads the block has 1 wave/SIMD (grid=512 =
// exactly 2 blocks/CU, so LDS headroom can't add blocks) and phases A+B
// ran at ~25% of their VALU-issue bound (47us vs ~12us of work) -> latency
// bound from too few waves. 8 waves doubles per-SIMD wave count for the
// data-parallel phases with HALVED per-thread work (no new reductions --
// unlike round-5's GRU K-split which added shfl/gate overhead).
// GRU phase keeps the proven 4-wave structure on waves 0-3 (t<256);
// waves 4-7 execute the same barrier sequence idle (wave->SIMD round-robin
// keeps 1 GRU wave per SIMD per block, unchanged from round 6).
// __launch_bounds__(512,4): 4 waves/EU = 2 blocks/CU, VGPR cap 128 (have ~92).
// =====================================================================
__global__ __launch_bounds__(512,4) void k_fused(
    const float* __restrict__ x, const int* __restrict__ ei,
    const float* __restrict__ W1, const float* __restrict__ a_s, const float* __restrict__ a_d,
    const float* __restrict__ b1,
    const uint4* __restrict__ W2i, const float* __restrict__ a_s2, const float* __restrict__ a_d2,
    const float* __restrict__ b2, const float* __restrict__ gam, const float* __restrict__ bet,
    const u32* __restrict__ wpk,
    const float* __restrict__ bi1, const float* __restrict__ bh1,
    const float* __restrict__ bi2, const float* __restrict__ bh2,
    const float* __restrict__ Wf, const float* __restrict__ bfv,
    void* __restrict__ outp, const int* __restrict__ flag)
{
    const int b = blockIdx.x, t = threadIdx.x;

    __shared__ __align__(16) float s_x[NN][12];
    __shared__ __align__(16) u16 s_h[NN][520];                  // pre-agg h, then h1
    __shared__ __align__(16) u32 s_aspk[HEADS*32], s_adpk[HEADS*32];
    __shared__ float s_es[NN][HEADS], s_ed[NN][HEADS];
    __shared__ unsigned char s_src[ETOT], s_dst[ETOT];
    __shared__ float s_al[HEADS][ETOT];
    __shared__ u32 s_mx[NN*HEADS];
    __shared__ float s_sm[NN*HEADS], s_inv[NN*HEADS];
    __shared__ int s_cnt[NN], s_off[NN], s_fil[NN];
    __shared__ short s_lst[ETOT];
    __shared__ float s_h2[NN][HID];
    __shared__ __align__(16) u32 s_x1[64*16];                   // gru input u16[64][32]
    __shared__ __align__(16) u32 s_g1[2][32];
    __shared__ __align__(16) u32 s_g2[2][32];
    __shared__ float s_h2f[64];

    // ---------------- phase A: GAT layer 1 ----------------
    for(int i=t;i<NN*T_IN;i+=512) s_x[i/12][i%12] = x[b*NN*T_IN + i];
    if(t<256){
        s_aspk[t]=packf16(a_s[2*t],a_s[2*t+1]);
        s_adpk[t]=packf16(a_d[2*t],a_d[2*t+1]);
        s_mx[t]=0u; s_sm[t]=0.f;
    }
    if(t<EPB){
        s_src[t] = (unsigned char)(ei[b*EPB+t] - b*NN);
        s_dst[t] = (unsigned char)(ei[(size_t)BATCH*EPB + b*EPB+t] - b*NN);
    }
    if(t<NN){ s_src[EPB+t]=s_dst[EPB+t]=(unsigned char)t; s_cnt[t]=0; s_fil[t]=0; }
    // one W1 column per thread, direct from global (L2 broadcast)
    v4f Wc0,Wc1,Wc2;
    Wc0.x=W1[0*F1+t]; Wc0.y=W1[1*F1+t]; Wc0.z=W1[2*F1+t]; Wc0.w=W1[3*F1+t];
    Wc1.x=W1[4*F1+t]; Wc1.y=W1[5*F1+t]; Wc1.z=W1[6*F1+t]; Wc1.w=W1[7*F1+t];
    Wc2.x=W1[8*F1+t]; Wc2.y=W1[9*F1+t]; Wc2.z=W1[10*F1+t]; Wc2.w=W1[11*F1+t];
    __syncthreads();

    for(int n=0;n<NN;n++){
        const float4* xp=(const float4*)s_x[n];
        float4 xa=xp[0], xb=xp[1], xc=xp[2];
        float A=0.f;
        A=fmaf(xa.x,Wc0.x,A); A=fmaf(xa.y,Wc0.y,A); A=fmaf(xa.z,Wc0.z,A); A=fmaf(xa.w,Wc0.w,A);
        A=fmaf(xb.x,Wc1.x,A); A=fmaf(xb.y,Wc1.y,A); A=fmaf(xb.z,Wc1.z,A); A=fmaf(xb.w,Wc1.w,A);
        A=fmaf(xc.x,Wc2.x,A); A=fmaf(xc.y,Wc2.y,A); A=fmaf(xc.z,Wc2.z,A); A=fmaf(xc.w,Wc2.w,A);
        s_h[n][t]=f2h16(A);
    }
    for(int e=t;e<ETOT;e+=512) atomicAdd(&s_cnt[s_dst[e]],1);
    __syncthreads();

    if(t<256){
        int n=t&31, hd=t>>5;
        const v4u* hp=(const v4u*)((const u16*)s_h[n] + hd*64);
        v4u h0=hp[0],h1=hp[1],h2=hp[2],h3=hp[3],h4=hp[4],h5=hp[5],h6=hp[6],h7=hp[7];
        const v4u* ap=(const v4u*)&s_aspk[hd*32];
        const v4u* dp=(const v4u*)&s_adpk[hd*32];
        float e1=0.f,e2=0.f;
        { v4u w=ap[0]; DOT4(e1,h0,w); w=ap[1]; DOT4(e1,h1,w); w=ap[2]; DOT4(e1,h2,w); w=ap[3]; DOT4(e1,h3,w);
          w=ap[4]; DOT4(e1,h4,w); w=ap[5]; DOT4(e1,h5,w); w=ap[6]; DOT4(e1,h6,w); w=ap[7]; DOT4(e1,h7,w); }
        { v4u w=dp[0]; DOT4(e2,h0,w); w=dp[1]; DOT4(e2,h1,w); w=dp[2]; DOT4(e2,h2,w); w=dp[3]; DOT4(e2,h3,w);
          w=dp[4]; DOT4(e2,h4,w); w=dp[5]; DOT4(e2,h5,w); w=dp[6]; DOT4(e2,h6,w); w=dp[7]; DOT4(e2,h7,w); }
        s_es[n][hd]=e1; s_ed[n][hd]=e2;
    }
    if(t==0){ int o=0; for(int i=0;i<NN;i++){ s_off[i]=o; o+=s_cnt[i]; } }
    __syncthreads();

    for(int e=t;e<ETOT;e+=512){
        int d=s_dst[e]; int p=atomicAdd(&s_fil[d],1); s_lst[s_off[d]+p]=(short)e;
    }
    for(int i=t;i<ETOT*HEADS;i+=512){
        int hd=i/ETOT, e=i-hd*ETOT;
        int sr=s_src[e], d=s_dst[e];
        float v = s_es[sr][hd]+s_ed[d][hd];
        v = v>0.f? v : 0.2f*v;
        s_al[hd][e]=v;
        atomicMax(&s_mx[d*8+hd], fenc(v));
    }
    __syncthreads();

    for(int i=t;i<ETOT*HEADS;i+=512){
        int hd=i/ETOT, e=i-hd*ETOT;
        int d=s_dst[e];
        float p=__expf(s_al[hd][e]-fdec(s_mx[d*8+hd]));
        s_al[hd][e]=p;
        atomicAdd(&s_sm[d*8+hd], p);
    }
    __syncthreads();
    if(t<256) s_inv[t]=1.f/(s_sm[t]+1e-16f);
    __syncthreads();

    // aggregation: 512 items = (d, hd, ch); h1 staged in regs, written after barrier
    u32 res[16];
    const int dA=t&31, hdA=(t>>5)&7, chA=t>>8;
    {
        int o=s_off[dA], cnt=s_cnt[dA];
        float inv=s_inv[dA*8+hdA];
        v4f a0=0,a1=0,a2=0,a3=0,a4=0,a5=0,a6=0,a7=0;
        for(int i=0;i<cnt;i++){
            int e=s_lst[o+i]; float av=s_al[hdA][e]; int sr=s_src[e];
            const v4u* hp=(const v4u*)((const u16*)s_h[sr] + hdA*64 + chA*32);
            v4u p0=hp[0],p1=hp[1],p2=hp[2],p3=hp[3];
            a0.x=fmaf(av,lof(p0.x),a0.x); a0.y=fmaf(av,hif(p0.x),a0.y);
            a0.z=fmaf(av,lof(p0.y),a0.z); a0.w=fmaf(av,hif(p0.y),a0.w);
            a1.x=fmaf(av,lof(p0.z),a1.x); a1.y=fmaf(av,hif(p0.z),a1.y);
            a1.z=fmaf(av,lof(p0.w),a1.z); a1.w=fmaf(av,hif(p0.w),a1.w);
            a2.x=fmaf(av,lof(p1.x),a2.x); a2.y=fmaf(av,hif(p1.x),a2.y);
            a2.z=fmaf(av,lof(p1.y),a2.z); a2.w=fmaf(av,hif(p1.y),a2.w);
            a3.x=fmaf(av,lof(p1.z),a3.x); a3.y=fmaf(av,hif(p1.z),a3.y);
            a3.z=fmaf(av,lof(p1.w),a3.z); a3.w=fmaf(av,hif(p1.w),a3.w);
            a4.x=fmaf(av,lof(p2.x),a4.x); a4.y=fmaf(av,hif(p2.x),a4.y);
            a4.z=fmaf(av,lof(p2.y),a4.z); a4.w=fmaf(av,hif(p2.y),a4.w);
            a5.x=fmaf(av,lof(p2.z),a5.x); a5.y=fmaf(av,hif(p2.z),a5.y);
            a5.z=fmaf(av,lof(p2.w),a5.z); a5.w=fmaf(av,hif(p2.w),a5.w);
            a6.x=fmaf(av,lof(p3.x),a6.x); a6.y=fmaf(av,hif(p3.x),a6.y);
            a6.z=fmaf(av,lof(p3.y),a6.z); a6.w=fmaf(av,hif(p3.y),a6.w);
            a7.x=fmaf(av,lof(p3.z),a7.x); a7.y=fmaf(av,hif(p3.z),a7.y);
            a7.z=fmaf(av,lof(p3.w),a7.z); a7.w=fmaf(av,hif(p3.w),a7.w);
        }
        const float* bp = b1 + hdA*64 + chA*32;
        res[0] = packf16(elu1(a0.x*inv+bp[0]),  elu1(a0.y*inv+bp[1]));
        res[1] = packf16(elu1(a0.z*inv+bp[2]),  elu1(a0.w*inv+bp[3]));
        res[2] = packf16(elu1(a1.x*inv+bp[4]),  elu1(a1.y*inv+bp[5]));
        res[3] = packf16(elu1(a1.z*inv+bp[6]),  elu1(a1.w*inv+bp[7]));
        res[4] = packf16(elu1(a2.x*inv+bp[8]),  elu1(a2.y*inv+bp[9]));
        res[5] = packf16(elu1(a2.z*inv+bp[10]), elu1(a2.w*inv+bp[11]));
        res[6] = packf16(elu1(a3.x*inv+bp[12]), elu1(a3.y*inv+bp[13]));
        res[7] = packf16(elu1(a3.z*inv+bp[14]), elu1(a3.w*inv+bp[15]));
        res[8] = packf16(elu1(a4.x*inv+bp[16]), elu1(a4.y*inv+bp[17]));
        res[9] = packf16(elu1(a4.z*inv+bp[18]), elu1(a4.w*inv+bp[19]));
        res[10]= packf16(elu1(a5.x*inv+bp[20]), elu1(a5.y*inv+bp[21]));
        res[11]= packf16(elu1(a5.z*inv+bp[22]), elu1(a5.w*inv+bp[23]));
        res[12]= packf16(elu1(a6.x*inv+bp[24]), elu1(a6.y*inv+bp[25]));
        res[13]= packf16(elu1(a6.z*inv+bp[26]), elu1(a6.w*inv+bp[27]));
        res[14]= packf16(elu1(a7.x*inv+bp[28]), elu1(a7.y*inv+bp[29]));
        res[15]= packf16(elu1(a7.z*inv+bp[30]), elu1(a7.w*inv+bp[31]));
    }
    __syncthreads();     // everyone done READING s_h / s_al
    {   // write h1 into s_h (u32 row stride 260), reset gat2 scratch
        u32* rw = ((u32*)s_h) + dA*260 + hdA*32 + chA*16;
        #pragma unroll
        for(int i=0;i<16;i++) rw[i]=res[i];
    }
    if(t<NN){ s_fil[t]=0; s_mx[t]=0u; s_sm[t]=0.f; }
    __syncthreads();

    // ---------------- phase B: GAT layer 2 + LayerNorm ----------------
    {
        // 512 threads: 4 rows x 1 col each. wave w -> rows 4w..4w+3, lane -> col
        int n0=(t>>6)<<2, j=t&63;
        const u32* r0=((const u32*)s_h)+(n0+0)*260;
        const u32* r1=((const u32*)s_h)+(n0+1)*260;
        const u32* r2=((const u32*)s_h)+(n0+2)*260;
        const u32* r3=((const u32*)s_h)+(n0+3)*260;
        float a0=0,a1=0,a2=0,a3=0;
        for(int kb=0;kb<64;kb++){
            uint4 A0=*(const uint4*)&r0[kb*4];
            uint4 A1=*(const uint4*)&r1[kb*4];
            uint4 A2=*(const uint4*)&r2[kb*4];
            uint4 A3=*(const uint4*)&r3[kb*4];
            uint4 w0=W2i[kb*64+j];
            a0=dot2(A0.x,w0.x,a0); a0=dot2(A0.y,w0.y,a0); a0=dot2(A0.z,w0.z,a0); a0=dot2(A0.w,w0.w,a0);
            a1=dot2(A1.x,w0.x,a1); a1=dot2(A1.y,w0.y,a1); a1=dot2(A1.z,w0.z,a1); a1=dot2(A1.w,w0.w,a1);
            a2=dot2(A2.x,w0.x,a2); a2=dot2(A2.y,w0.y,a2); a2=dot2(A2.z,w0.z,a2); a2=dot2(A2.w,w0.w,a2);
            a3=dot2(A3.x,w0.x,a3); a3=dot2(A3.y,w0.y,a3); a3=dot2(A3.z,w0.z,a3); a3=dot2(A3.w,w0.w,a3);
        }
        s_h2[n0+0][j]=a0; s_h2[n0+1][j]=a1; s_h2[n0+2][j]=a2; s_h2[n0+3][j]=a3;
    }
    __syncthreads();

    if(t<256){
        int n=t>>3, g=t&7;
        float e1=0,e2=0;
        #pragma unroll
        for(int cc=0; cc<8; cc++){
            float hv = s_h2[n][g*8+cc];
            e1 += hv*a_s2[g*8+cc];
            e2 += hv*a_d2[g*8+cc];
        }
        #pragma unroll
        for(int m=1;m<8;m<<=1){ e1 += __shfl_xor(e1,m,64); e2 += __shfl_xor(e2,m,64); }
        if(g==0){ s_es[n][0]=e1; s_ed[n][0]=e2; }
    }
    __syncthreads();

    for(int e=t;e<ETOT;e+=512){
        int d=s_dst[e];
        float v = s_es[s_src[e]][0] + s_ed[d][0];
        v = v>0.f? v:0.2f*v;
        s_al[0][e]=v;
        atomicMax(&s_mx[d], fenc(v));
    }
    __syncthreads();

    for(int e=t;e<ETOT;e+=512){
        int d=s_dst[e];
        float p=__expf(s_al[0][e]-fdec(s_mx[d]));
        s_al[0][e]=p;
        atomicAdd(&s_sm[d], p);
    }
    __syncthreads();
    if(t<NN) s_inv[t]=1.f/(s_sm[t]+1e-16f);
    __syncthreads();

    if(t<256){
        int n=t>>3, g=t&7;
        v4f a0=0, a1=0;
        int o=s_off[n], cnt=s_cnt[n];
        float inv=s_inv[n];
        for(int i=0;i<cnt;i++){
            int e=s_lst[o+i]; float a=s_al[0][e]; int sr=s_src[e];
            const float4* hp=(const float4*)&s_h2[sr][g*8];
            float4 v0=hp[0], v1=hp[1];
            a0.x=fmaf(a,v0.x,a0.x); a0.y=fmaf(a,v0.y,a0.y); a0.z=fmaf(a,v0.z,a0.z); a0.w=fmaf(a,v0.w,a0.w);
            a1.x=fmaf(a,v1.x,a1.x); a1.y=fmaf(a,v1.y,a1.y); a1.z=fmaf(a,v1.z,a1.z); a1.w=fmaf(a,v1.w,a1.w);
        }
        const float* bp=b2+g*8;
        float v0=elu1(a0.x*inv+bp[0]), v1=elu1(a0.y*inv+bp[1]);
        float v2=elu1(a0.z*inv+bp[2]), v3=elu1(a0.w*inv+bp[3]);
        float v4=elu1(a1.x*inv+bp[4]), v5=elu1(a1.y*inv+bp[5]);
        float v6=elu1(a1.z*inv+bp[6]), v7=elu1(a1.w*inv+bp[7]);
        float sum=v0+v1+v2+v3+v4+v5+v6+v7;
        float sq=v0*v0+v1*v1+v2*v2+v3*v3+v4*v4+v5*v5+v6*v6+v7*v7;
        #pragma unroll
        for(int m=1;m<8;m<<=1){ sum+=__shfl_xor(sum,m,64); sq+=__shfl_xor(sq,m,64); }
        float mu = sum*(1.f/64.f);
        float var = sq*(1.f/64.f) - mu*mu;
        float rs = rsqrtf(var + 1e-5f);
        // LN output straight into GRU input layout: u16 s_x1[c][n]
        u16* xw=(u16*)s_x1;
        int c=g*8;
        xw[(c+0)*NN+n]=f2h16((v0-mu)*rs*gam[c+0]+bet[c+0]);
        xw[(c+1)*NN+n]=f2h16((v1-mu)*rs*gam[c+1]+bet[c+1]);
        xw[(c+2)*NN+n]=f2h16((v2-mu)*rs*gam[c+2]+bet[c+2]);
        xw[(c+3)*NN+n]=f2h16((v3-mu)*rs*gam[c+3]+bet[c+3]);
        xw[(c+4)*NN+n]=f2h16((v4-mu)*rs*gam[c+4]+bet[c+4]);
        xw[(c+5)*NN+n]=f2h16((v5-mu)*rs*gam[c+5]+bet[c+5]);
        xw[(c+6)*NN+n]=f2h16((v6-mu)*rs*gam[c+6]+bet[c+6]);
        xw[(c+7)*NN+n]=f2h16((v7-mu)*rs*gam[c+7]+bet[c+7]);
    }
    if(t<32){ s_g1[0][t]=0u; s_g1[1][t]=0u; s_g2[0][t]=0u; s_g2[1][t]=0u; }
    __syncthreads();

    // ---------------- phase C: fused GRU (r6 4-wave structure on waves 0-3) ----------------
    {
        const int wave=t>>6, lane=t&63;
        const int layer=wave>>1;        // 0 = GRU1, 1 = GRU2 (waves 0-3 only)
        const int ublk=wave&1;
        const int uu=lane&31, s=lane>>5;
        const int u=ublk*32+uu;
        const bool gw = (t<256);        // GRU worker

        u32 wiR[16],wiZ[16],wiN[16],whR[16],whZ[16],whN[16];
        float br=0.f,bz=0.f,bxn=0.f,bhn=0.f;
        if(gw){
            const u32* wiu = wpk + (size_t)(layer*2+0)*6144;
            const u32* whu = wpk + (size_t)(layer*2+1)*6144;
            if(layer==0){
                #pragma unroll
                for(int k=0;k<8;k++){
                    wiR[k]=wiu[u*32+s*8+k];
                    wiZ[k]=wiu[(64+u)*32+s*8+k];
                    wiN[k]=wiu[(128+u)*32+s*8+k];
                }
                #pragma unroll
                for(int k=0;k<16;k++){
                    whR[k]=whu[u*32+s*16+k];
                    whZ[k]=whu[(64+u)*32+s*16+k];
                    whN[k]=whu[(128+u)*32+s*16+k];
                }
            } else {
                #pragma unroll
                for(int k=0;k<16;k++){
                    wiR[k]=wiu[u*32+s*16+k];
                    wiZ[k]=wiu[(64+u)*32+s*16+k];
                    wiN[k]=wiu[(128+u)*32+s*16+k];
                    whR[k]=whu[u*32+s*16+k];
                    whZ[k]=whu[(64+u)*32+s*16+k];
                    whN[k]=whu[(128+u)*32+s*16+k];
                }
            }
            const float* bi = layer? bi2:bi1;
            const float* bh = layer? bh2:bh1;
            br=bi[u]+bh[u]; bz=bi[64+u]+bh[64+u]; bxn=bi[128+u]; bhn=bh[128+u];
        }
        float h=0.f;

        for(int it=0; it<=64; ++it){
            const int pb=(it-1)&1, cb=it&1;
            bool act=false;
            float pr=0.f,pz=0.f,pxn=0.f,phn=0.f;
            if(gw){
                if(layer==0){
                    act=(it<64);
                    if(act){
                        const u32* xp=&s_x1[it*16+s*8];
                        const u32* hp=&s_g1[pb][s*16];
                        #pragma unroll
                        for(int k=0;k<8;k++){ u32 xv=xp[k]; pr=dot2(xv,wiR[k],pr); pz=dot2(xv,wiZ[k],pz); pxn=dot2(xv,wiN[k],pxn); }
                        #pragma unroll
                        for(int k=0;k<16;k++){ u32 hv=hp[k]; pr=dot2(hv,whR[k],pr); pz=dot2(hv,whZ[k],pz); phn=dot2(hv,whN[k],phn); }
                    }
                } else {
                    act=(it>=1);
                    if(act){
                        const u32* xp=&s_g1[pb][s*16];   // y1[it-1]
                        const u32* hp=&s_g2[pb][s*16];
                        #pragma unroll
                        for(int k=0;k<16;k++){
                            u32 xv=xp[k], hv=hp[k];
                            pr=dot2(xv,wiR[k],pr); pz=dot2(xv,wiZ[k],pz); pxn=dot2(xv,wiN[k],pxn);
                            pr=dot2(hv,whR[k],pr); pz=dot2(hv,whZ[k],pz); phn=dot2(hv,whN[k],phn);
                        }
                    }
                }
            }
            if(act){
                pr  += __shfl_xor(pr ,32,64);
                pz  += __shfl_xor(pz ,32,64);
                pxn += __shfl_xor(pxn,32,64);
                phn += __shfl_xor(phn,32,64);
                float r=sigm(pr+br), z=sigm(pz+bz);
                float n=tanh_(pxn+bxn + r*(phn+bhn));
                h=(1.f-z)*n + z*h;
                if(s==0){
                    u16 hv=f2h16(h);
                    if(layer==0) ((u16*)s_g1[cb])[u]=hv;
                    else { ((u16*)s_g2[cb])[u]=hv; if(it==64) s_h2f[u]=h; }
                }
            }
            __syncthreads();
        }
    }

    if(t<OUT_CH){
        float acc=bfv[t];
        const float4* wp=(const float4*)(Wf + t*64);
        const float4* hp=(const float4*)s_h2f;
        #pragma unroll
        for(int k=0;k<16;k++){
            float4 w=wp[k], v=hp[k];
            acc += w.x*v.x + w.y*v.y + w.z*v.z + w.w*v.w;
        }
        if(*flag) ((float*)outp)[b*OUT_CH+t]=acc;
        else      ((u16*)outp)[b*OUT_CH+t]=f2bf(acc);
    }
}

extern "C" void kernel_launch(void* const* d_in, const int* in_sizes, int n_in,
                              void* d_out, int out_size, void* d_ws, size_t ws_size,
                              hipStream_t stream)
{
    char* ws=(char*)d_ws;
    int* flag = (int*)ws;
    float* cf = (float*)(ws + 256);
    float* c_x   = cf; cf+=196608;
    float* c_W1  = cf; cf+=6144;
    float* c_as1 = cf; cf+=512;
    float* c_ad1 = cf; cf+=512;
    float* c_b1  = cf; cf+=512;
    float* c_as2 = cf; cf+=64;
    float* c_ad2 = cf; cf+=64;
    float* c_b2  = cf; cf+=64;
    float* c_gam = cf; cf+=64;
    float* c_bet = cf; cf+=64;
    float* c_bi1 = cf; cf+=192;
    float* c_bh1 = cf; cf+=192;
    float* c_bi2 = cf; cf+=192;
    float* c_bh2 = cf; cf+=192;
    float* c_Wf  = cf; cf+=576;
    float* c_bf  = cf; cf+=9;
    uintptr_t p = ((uintptr_t)cf + 255) & ~(uintptr_t)255;
    u16* c_W2i = (u16*)p;                        // 32768 f16 = 64 KB (interleaved)
    p = (p + 32768*2 + 255) & ~(uintptr_t)255;
    u32* wpk = (u32*)p;                          // 4*192*32 u32 = 96 KB (packed GRU weights)

    const int* ei = (const int*)d_in[1];

    CvtDesc d;
    const int srcIdx[16] = {0,2,3,4,5,7,8,9,10,11,14,15,18,19,20,21};
    void* dsts[16] = {c_x,c_W1,c_as1,c_ad1,c_b1,c_as2,c_ad2,c_b2,c_gam,c_bet,
                      c_bi1,c_bh1,c_bi2,c_bh2,c_Wf,c_bf};
    const int ns[16] = {196608,6144,512,512,512,64,64,64,64,64,
                        192,192,192,192,576,9};
    for(int i=0;i<16;i++){ d.src[i]=d_in[srcIdx[i]]; d.dst[i]=dsts[i]; d.n[i]=ns[i]; }

    k_setup <<<dim3(352),dim3(256),0,stream>>>((const u32*)d_in[0], d,
                                               d_in[6], c_W2i,
                                               d_in[12], d_in[13], d_in[16], d_in[17],
                                               wpk, flag);
    k_fused <<<dim3(BATCH),dim3(512),0,stream>>>(
        c_x, ei, c_W1, c_as1, c_ad1, c_b1,
        (const uint4*)c_W2i, c_as2, c_ad2, c_b2, c_gam, c_bet,
        wpk, c_bi1, c_bh1, c_bi2, c_bh2,
        c_Wf, c_bf, d_out, flag);
}

// Round 8
// 215.122 us; speedup vs baseline: 1.1833x; 1.1833x over previous
//
#include <hip/hip_runtime.h>
#include <hip/hip_bf16.h>
#include <stdint.h>

#define BATCH 512
#define NN 32
#define T_IN 12
#define HID 64
#define HEADS 8
#define OUT_CH 9
#define EPB (NN*8)       // 256 edges per batch (before self loops)
#define ETOT (EPB+NN)    // 288 with self loops
#define F1 (HEADS*HID)   // 512

using u16 = unsigned short;
using u32 = unsigned int;
typedef _Float16 f16;
typedef _Float16 f16x2 __attribute__((ext_vector_type(2)));
typedef u32 v4u __attribute__((ext_vector_type(4)));
typedef float v4f __attribute__((ext_vector_type(4)));

__device__ __forceinline__ float bf2f(u16 u){ return __uint_as_float(((u32)u)<<16); }
__device__ __forceinline__ u16 f2bf(float f){
    u32 x = __float_as_uint(f);
    u32 r = (x + 0x7FFFu + ((x>>16)&1u))>>16;
    return (u16)r;
}
__device__ __forceinline__ u32 packf16(float a, float b){
    f16x2 p; p.x=(f16)a; p.y=(f16)b; return __builtin_bit_cast(u32,p);
}
__device__ __forceinline__ u16 f2h16(float a){ f16 h=(f16)a; return __builtin_bit_cast(u16,h); }
__device__ __forceinline__ float lof(u32 w){ return (float)__builtin_bit_cast(f16x2,w).x; }
__device__ __forceinline__ float hif(u32 w){ return (float)__builtin_bit_cast(f16x2,w).y; }
__device__ __forceinline__ float dot2(u32 a, u32 b, float c){
#if __has_builtin(__builtin_amdgcn_fdot2)
    return __builtin_amdgcn_fdot2(__builtin_bit_cast(f16x2,a), __builtin_bit_cast(f16x2,b), c, false);
#else
    return fmaf(lof(a),lof(b), fmaf(hif(a),hif(b), c));
#endif
}
__device__ __forceinline__ float elu1(float x){ return x > 0.f ? x : (__expf(x)-1.f); }
__device__ __forceinline__ float sigm(float x){ return 1.f/(1.f+__expf(-x)); }
__device__ __forceinline__ float tanh_(float x){ return 1.f - 2.f/(__expf(2.f*x)+1.f); }
__device__ __forceinline__ u32 fenc(float v){
    u32 b=__float_as_uint(v);
    return (b&0x80000000u) ? ~b : (b|0x80000000u);
}
__device__ __forceinline__ float fdec(u32 k){
    return __uint_as_float((k&0x80000000u) ? (k&0x7FFFFFFFu) : ~k);
}

#define DOT4(acc,A,W) do{ acc=dot2(A.x,W.x,acc); acc=dot2(A.y,W.y,acc); \
                          acc=dot2(A.z,W.z,acc); acc=dot2(A.w,W.w,acc); }while(0)

#define PIN(v) asm("" : "+v"(v))

// ------------------------------------------------ canonicalize inputs into ws (fp32)
struct CvtDesc {
    const void* src[16];
    void*       dst[16];
    int         n[16];
};

// merged detect + convert + W2 interleave + GRU weight packing (one launch).
__global__ __launch_bounds__(256) void k_setup(
    const u32* __restrict__ xw, CvtDesc d,
    const void* __restrict__ W2src, u16* __restrict__ W2i,
    const void* __restrict__ Wi1, const void* __restrict__ Wh1,
    const void* __restrict__ Wi2, const void* __restrict__ Wh2,
    u32* __restrict__ wpk, int* __restrict__ flag)
{
    __shared__ int cnt;
    if(threadIdx.x==0) cnt=0;
    __syncthreads();
    int c=0;
    for(int i=threadIdx.x;i<4096;i+=256){
        u32 w=xw[i];
        if(w & 0x7FFFFFFFu){
            u32 el=(w>>7)&0xFFu;
            if(el>=0x90u) c++;
        }
    }
    atomicAdd(&cnt,c);
    __syncthreads();
    const int f = (cnt>256) ? 1 : 0;   // 1 = fp32 inputs, 0 = bf16
    if(blockIdx.x==0 && threadIdx.x==0) *flag=f;

    const int bk=blockIdx.x;
    if(bk<128){
        int seg=bk>>3, sub=bk&7;
        const void* s=d.src[seg];
        float* o=(float*)d.dst[seg];
        int n=d.n[seg];
        for(int i=sub*256+threadIdx.x;i<n;i+=2048)
            o[i] = f ? ((const float*)s)[i] : bf2f(((const u16*)s)[i]);
    } else if(bk<256){
        // W2 [512][64] -> interleaved fp16 W2i[(k>>3)*64+j][k&7]
        int i=(bk-128)*256+threadIdx.x;
        int k=i>>6, j=i&63;
        float v = f? ((const float*)W2src)[i] : bf2f(((const u16*)W2src)[i]);
        W2i[ (((size_t)(k>>3)*64 + j)<<3) + (k&7) ] = f2h16(v);
    } else {
        // GRU weights -> packed fp16 [4][192 rows][32 u32] (K=64, Wi1 zero-padded)
        int w=(bk-256)*256+threadIdx.x;
        int m=w/6144;
        int rem=w-m*6144;
        int row=rem>>5, kw=rem&31;
        const void* s=(m==0)?Wi1:(m==1)?Wh1:(m==2)?Wi2:Wh2;
        int K=(m==0)?32:64;
        int k0=2*kw, k1=k0+1;
        float v0=0.f, v1=0.f;
        if(k0<K) v0 = f? ((const float*)s)[row*K+k0] : bf2f(((const u16*)s)[row*K+k0]);
        if(k1<K) v1 = f? ((const float*)s)[row*K+k1] : bf2f(((const u16*)s)[row*K+k1]);
        wpk[w]=packf16(v0,v1);
    }
}

// =====================================================================
// k_ab: GAT1 -> GAT2+LN fused, 512 threads / 8 waves, one block per batch.
// Round-7 lesson: A+B (needs waves, ~64 VGPR) and GRU (needs ~136 regs)
// have incompatible resource profiles -- fusing them forces a block-wide
// register cap that spilled the GRU (17MB scratch writes). Split along
// that boundary: this kernel holds ONLY the wave-hungry phases at
// __launch_bounds__(512,4) (16 waves/CU, no spill), writes LN output to
// hlng; the GRU runs in its own 256-thread kernel with full reg budget.
// A+B logic verbatim from round 7 (harness-verified correct there).
// =====================================================================
__global__ __launch_bounds__(512,4) void k_ab(
    const float* __restrict__ x, const int* __restrict__ ei,
    const float* __restrict__ W1, const float* __restrict__ a_s, const float* __restrict__ a_d,
    const float* __restrict__ b1,
    const uint4* __restrict__ W2i, const float* __restrict__ a_s2, const float* __restrict__ a_d2,
    const float* __restrict__ b2, const float* __restrict__ gam, const float* __restrict__ bet,
    float* __restrict__ hlng)
{
    const int b = blockIdx.x, t = threadIdx.x;

    __shared__ __align__(16) float s_x[NN][12];
    __shared__ __align__(16) u16 s_h[NN][520];                  // pre-agg h, then h1
    __shared__ __align__(16) u32 s_aspk[HEADS*32], s_adpk[HEADS*32];
    __shared__ float s_es[NN][HEADS], s_ed[NN][HEADS];
    __shared__ unsigned char s_src[ETOT], s_dst[ETOT];
    __shared__ float s_al[HEADS][ETOT];
    __shared__ u32 s_mx[NN*HEADS];
    __shared__ float s_sm[NN*HEADS], s_inv[NN*HEADS];
    __shared__ int s_cnt[NN], s_off[NN], s_fil[NN];
    __shared__ short s_lst[ETOT];
    __shared__ float s_h2[NN][HID];

    // ---------------- phase A: GAT layer 1 ----------------
    for(int i=t;i<NN*T_IN;i+=512) s_x[i/12][i%12] = x[b*NN*T_IN + i];
    if(t<256){
        s_aspk[t]=packf16(a_s[2*t],a_s[2*t+1]);
        s_adpk[t]=packf16(a_d[2*t],a_d[2*t+1]);
        s_mx[t]=0u; s_sm[t]=0.f;
    }
    if(t<EPB){
        s_src[t] = (unsigned char)(ei[b*EPB+t] - b*NN);
        s_dst[t] = (unsigned char)(ei[(size_t)BATCH*EPB + b*EPB+t] - b*NN);
    }
    if(t<NN){ s_src[EPB+t]=s_dst[EPB+t]=(unsigned char)t; s_cnt[t]=0; s_fil[t]=0; }
    // one W1 column per thread, direct from global (L2 broadcast)
    v4f Wc0,Wc1,Wc2;
    Wc0.x=W1[0*F1+t]; Wc0.y=W1[1*F1+t]; Wc0.z=W1[2*F1+t]; Wc0.w=W1[3*F1+t];
    Wc1.x=W1[4*F1+t]; Wc1.y=W1[5*F1+t]; Wc1.z=W1[6*F1+t]; Wc1.w=W1[7*F1+t];
    Wc2.x=W1[8*F1+t]; Wc2.y=W1[9*F1+t]; Wc2.z=W1[10*F1+t]; Wc2.w=W1[11*F1+t];
    __syncthreads();

    for(int n=0;n<NN;n++){
        const float4* xp=(const float4*)s_x[n];
        float4 xa=xp[0], xb=xp[1], xc=xp[2];
        float A=0.f;
        A=fmaf(xa.x,Wc0.x,A); A=fmaf(xa.y,Wc0.y,A); A=fmaf(xa.z,Wc0.z,A); A=fmaf(xa.w,Wc0.w,A);
        A=fmaf(xb.x,Wc1.x,A); A=fmaf(xb.y,Wc1.y,A); A=fmaf(xb.z,Wc1.z,A); A=fmaf(xb.w,Wc1.w,A);
        A=fmaf(xc.x,Wc2.x,A); A=fmaf(xc.y,Wc2.y,A); A=fmaf(xc.z,Wc2.z,A); A=fmaf(xc.w,Wc2.w,A);
        s_h[n][t]=f2h16(A);
    }
    for(int e=t;e<ETOT;e+=512) atomicAdd(&s_cnt[s_dst[e]],1);
    __syncthreads();

    if(t<256){
        int n=t&31, hd=t>>5;
        const v4u* hp=(const v4u*)((const u16*)s_h[n] + hd*64);
        v4u h0=hp[0],h1=hp[1],h2=hp[2],h3=hp[3],h4=hp[4],h5=hp[5],h6=hp[6],h7=hp[7];
        const v4u* ap=(const v4u*)&s_aspk[hd*32];
        const v4u* dp=(const v4u*)&s_adpk[hd*32];
        float e1=0.f,e2=0.f;
        { v4u w=ap[0]; DOT4(e1,h0,w); w=ap[1]; DOT4(e1,h1,w); w=ap[2]; DOT4(e1,h2,w); w=ap[3]; DOT4(e1,h3,w);
          w=ap[4]; DOT4(e1,h4,w); w=ap[5]; DOT4(e1,h5,w); w=ap[6]; DOT4(e1,h6,w); w=ap[7]; DOT4(e1,h7,w); }
        { v4u w=dp[0]; DOT4(e2,h0,w); w=dp[1]; DOT4(e2,h1,w); w=dp[2]; DOT4(e2,h2,w); w=dp[3]; DOT4(e2,h3,w);
          w=dp[4]; DOT4(e2,h4,w); w=dp[5]; DOT4(e2,h5,w); w=dp[6]; DOT4(e2,h6,w); w=dp[7]; DOT4(e2,h7,w); }
        s_es[n][hd]=e1; s_ed[n][hd]=e2;
    }
    if(t==0){ int o=0; for(int i=0;i<NN;i++){ s_off[i]=o; o+=s_cnt[i]; } }
    __syncthreads();

    for(int e=t;e<ETOT;e+=512){
        int d=s_dst[e]; int p=atomicAdd(&s_fil[d],1); s_lst[s_off[d]+p]=(short)e;
    }
    for(int i=t;i<ETOT*HEADS;i+=512){
        int hd=i/ETOT, e=i-hd*ETOT;
        int sr=s_src[e], d=s_dst[e];
        float v = s_es[sr][hd]+s_ed[d][hd];
        v = v>0.f? v : 0.2f*v;
        s_al[hd][e]=v;
        atomicMax(&s_mx[d*8+hd], fenc(v));
    }
    __syncthreads();

    for(int i=t;i<ETOT*HEADS;i+=512){
        int hd=i/ETOT, e=i-hd*ETOT;
        int d=s_dst[e];
        float p=__expf(s_al[hd][e]-fdec(s_mx[d*8+hd]));
        s_al[hd][e]=p;
        atomicAdd(&s_sm[d*8+hd], p);
    }
    __syncthreads();
    if(t<256) s_inv[t]=1.f/(s_sm[t]+1e-16f);
    __syncthreads();

    // aggregation: 512 items = (d, hd, ch); h1 staged in regs, written after barrier
    u32 res[16];
    const int dA=t&31, hdA=(t>>5)&7, chA=t>>8;
    {
        int o=s_off[dA], cnt=s_cnt[dA];
        float inv=s_inv[dA*8+hdA];
        v4f a0=0,a1=0,a2=0,a3=0,a4=0,a5=0,a6=0,a7=0;
        for(int i=0;i<cnt;i++){
            int e=s_lst[o+i]; float av=s_al[hdA][e]; int sr=s_src[e];
            const v4u* hp=(const v4u*)((const u16*)s_h[sr] + hdA*64 + chA*32);
            v4u p0=hp[0],p1=hp[1],p2=hp[2],p3=hp[3];
            a0.x=fmaf(av,lof(p0.x),a0.x); a0.y=fmaf(av,hif(p0.x),a0.y);
            a0.z=fmaf(av,lof(p0.y),a0.z); a0.w=fmaf(av,hif(p0.y),a0.w);
            a1.x=fmaf(av,lof(p0.z),a1.x); a1.y=fmaf(av,hif(p0.z),a1.y);
            a1.z=fmaf(av,lof(p0.w),a1.z); a1.w=fmaf(av,hif(p0.w),a1.w);
            a2.x=fmaf(av,lof(p1.x),a2.x); a2.y=fmaf(av,hif(p1.x),a2.y);
            a2.z=fmaf(av,lof(p1.y),a2.z); a2.w=fmaf(av,hif(p1.y),a2.w);
            a3.x=fmaf(av,lof(p1.z),a3.x); a3.y=fmaf(av,hif(p1.z),a3.y);
            a3.z=fmaf(av,lof(p1.w),a3.z); a3.w=fmaf(av,hif(p1.w),a3.w);
            a4.x=fmaf(av,lof(p2.x),a4.x); a4.y=fmaf(av,hif(p2.x),a4.y);
            a4.z=fmaf(av,lof(p2.y),a4.z); a4.w=fmaf(av,hif(p2.y),a4.w);
            a5.x=fmaf(av,lof(p2.z),a5.x); a5.y=fmaf(av,hif(p2.z),a5.y);
            a5.z=fmaf(av,lof(p2.w),a5.z); a5.w=fmaf(av,hif(p2.w),a5.w);
            a6.x=fmaf(av,lof(p3.x),a6.x); a6.y=fmaf(av,hif(p3.x),a6.y);
            a6.z=fmaf(av,lof(p3.y),a6.z); a6.w=fmaf(av,hif(p3.y),a6.w);
            a7.x=fmaf(av,lof(p3.z),a7.x); a7.y=fmaf(av,hif(p3.z),a7.y);
            a7.z=fmaf(av,lof(p3.w),a7.z); a7.w=fmaf(av,hif(p3.w),a7.w);
        }
        const float* bp = b1 + hdA*64 + chA*32;
        res[0] = packf16(elu1(a0.x*inv+bp[0]),  elu1(a0.y*inv+bp[1]));
        res[1] = packf16(elu1(a0.z*inv+bp[2]),  elu1(a0.w*inv+bp[3]));
        res[2] = packf16(elu1(a1.x*inv+bp[4]),  elu1(a1.y*inv+bp[5]));
        res[3] = packf16(elu1(a1.z*inv+bp[6]),  elu1(a1.w*inv+bp[7]));
        res[4] = packf16(elu1(a2.x*inv+bp[8]),  elu1(a2.y*inv+bp[9]));
        res[5] = packf16(elu1(a2.z*inv+bp[10]), elu1(a2.w*inv+bp[11]));
        res[6] = packf16(elu1(a3.x*inv+bp[12]), elu1(a3.y*inv+bp[13]));
        res[7] = packf16(elu1(a3.z*inv+bp[14]), elu1(a3.w*inv+bp[15]));
        res[8] = packf16(elu1(a4.x*inv+bp[16]), elu1(a4.y*inv+bp[17]));
        res[9] = packf16(elu1(a4.z*inv+bp[18]), elu1(a4.w*inv+bp[19]));
        res[10]= packf16(elu1(a5.x*inv+bp[20]), elu1(a5.y*inv+bp[21]));
        res[11]= packf16(elu1(a5.z*inv+bp[22]), elu1(a5.w*inv+bp[23]));
        res[12]= packf16(elu1(a6.x*inv+bp[24]), elu1(a6.y*inv+bp[25]));
        res[13]= packf16(elu1(a6.z*inv+bp[26]), elu1(a6.w*inv+bp[27]));
        res[14]= packf16(elu1(a7.x*inv+bp[28]), elu1(a7.y*inv+bp[29]));
        res[15]= packf16(elu1(a7.z*inv+bp[30]), elu1(a7.w*inv+bp[31]));
    }
    __syncthreads();     // everyone done READING s_h / s_al
    {   // write h1 into s_h (u32 row stride 260), reset gat2 scratch
        u32* rw = ((u32*)s_h) + dA*260 + hdA*32 + chA*16;
        #pragma unroll
        for(int i=0;i<16;i++) rw[i]=res[i];
    }
    if(t<NN){ s_fil[t]=0; s_mx[t]=0u; s_sm[t]=0.f; }
    __syncthreads();

    // ---------------- phase B: GAT layer 2 + LayerNorm ----------------
    {
        // 512 threads: 4 rows x 1 col each. wave w -> rows 4w..4w+3, lane -> col
        int n0=(t>>6)<<2, j=t&63;
        const u32* r0=((const u32*)s_h)+(n0+0)*260;
        const u32* r1=((const u32*)s_h)+(n0+1)*260;
        const u32* r2=((const u32*)s_h)+(n0+2)*260;
        const u32* r3=((const u32*)s_h)+(n0+3)*260;
        float a0=0,a1=0,a2=0,a3=0;
        for(int kb=0;kb<64;kb++){
            uint4 A0=*(const uint4*)&r0[kb*4];
            uint4 A1=*(const uint4*)&r1[kb*4];
            uint4 A2=*(const uint4*)&r2[kb*4];
            uint4 A3=*(const uint4*)&r3[kb*4];
            uint4 w0=W2i[kb*64+j];
            a0=dot2(A0.x,w0.x,a0); a0=dot2(A0.y,w0.y,a0); a0=dot2(A0.z,w0.z,a0); a0=dot2(A0.w,w0.w,a0);
            a1=dot2(A1.x,w0.x,a1); a1=dot2(A1.y,w0.y,a1); a1=dot2(A1.z,w0.z,a1); a1=dot2(A1.w,w0.w,a1);
            a2=dot2(A2.x,w0.x,a2); a2=dot2(A2.y,w0.y,a2); a2=dot2(A2.z,w0.z,a2); a2=dot2(A2.w,w0.w,a2);
            a3=dot2(A3.x,w0.x,a3); a3=dot2(A3.y,w0.y,a3); a3=dot2(A3.z,w0.z,a3); a3=dot2(A3.w,w0.w,a3);
        }
        s_h2[n0+0][j]=a0; s_h2[n0+1][j]=a1; s_h2[n0+2][j]=a2; s_h2[n0+3][j]=a3;
    }
    __syncthreads();

    if(t<256){
        int n=t>>3, g=t&7;
        float e1=0,e2=0;
        #pragma unroll
        for(int cc=0; cc<8; cc++){
            float hv = s_h2[n][g*8+cc];
            e1 += hv*a_s2[g*8+cc];
            e2 += hv*a_d2[g*8+cc];
        }
        #pragma unroll
        for(int m=1;m<8;m<<=1){ e1 += __shfl_xor(e1,m,64); e2 += __shfl_xor(e2,m,64); }
        if(g==0){ s_es[n][0]=e1; s_ed[n][0]=e2; }
    }
    __syncthreads();

    for(int e=t;e<ETOT;e+=512){
        int d=s_dst[e];
        float v = s_es[s_src[e]][0] + s_ed[d][0];
        v = v>0.f? v:0.2f*v;
        s_al[0][e]=v;
        atomicMax(&s_mx[d], fenc(v));
    }
    __syncthreads();

    for(int e=t;e<ETOT;e+=512){
        int d=s_dst[e];
        float p=__expf(s_al[0][e]-fdec(s_mx[d]));
        s_al[0][e]=p;
        atomicAdd(&s_sm[d], p);
    }
    __syncthreads();
    if(t<NN) s_inv[t]=1.f/(s_sm[t]+1e-16f);
    __syncthreads();

    if(t<256){
        int n=t>>3, g=t&7;
        v4f a0=0, a1=0;
        int o=s_off[n], cnt=s_cnt[n];
        float inv=s_inv[n];
        for(int i=0;i<cnt;i++){
            int e=s_lst[o+i]; float a=s_al[0][e]; int sr=s_src[e];
            const float4* hp=(const float4*)&s_h2[sr][g*8];
            float4 v0=hp[0], v1=hp[1];
            a0.x=fmaf(a,v0.x,a0.x); a0.y=fmaf(a,v0.y,a0.y); a0.z=fmaf(a,v0.z,a0.z); a0.w=fmaf(a,v0.w,a0.w);
            a1.x=fmaf(a,v1.x,a1.x); a1.y=fmaf(a,v1.y,a1.y); a1.z=fmaf(a,v1.z,a1.z); a1.w=fmaf(a,v1.w,a1.w);
        }
        const float* bp=b2+g*8;
        float v0=elu1(a0.x*inv+bp[0]), v1=elu1(a0.y*inv+bp[1]);
        float v2=elu1(a0.z*inv+bp[2]), v3=elu1(a0.w*inv+bp[3]);
        float v4=elu1(a1.x*inv+bp[4]), v5=elu1(a1.y*inv+bp[5]);
        float v6=elu1(a1.z*inv+bp[6]), v7=elu1(a1.w*inv+bp[7]);
        float sum=v0+v1+v2+v3+v4+v5+v6+v7;
        float sq=v0*v0+v1*v1+v2*v2+v3*v3+v4*v4+v5*v5+v6*v6+v7*v7;
        #pragma unroll
        for(int m=1;m<8;m<<=1){ sum+=__shfl_xor(sum,m,64); sq+=__shfl_xor(sq,m,64); }
        float mu = sum*(1.f/64.f);
        float var = sq*(1.f/64.f) - mu*mu;
        float rs = rsqrtf(var + 1e-5f);
        float* op = hlng + (size_t)b*HID*NN;
        int c=g*8;
        op[(c+0)*NN+n]=(v0-mu)*rs*gam[c+0]+bet[c+0];
        op[(c+1)*NN+n]=(v1-mu)*rs*gam[c+1]+bet[c+1];
        op[(c+2)*NN+n]=(v2-mu)*rs*gam[c+2]+bet[c+2];
        op[(c+3)*NN+n]=(v3-mu)*rs*gam[c+3]+bet[c+3];
        op[(c+4)*NN+n]=(v4-mu)*rs*gam[c+4]+bet[c+4];
        op[(c+5)*NN+n]=(v5-mu)*rs*gam[c+5]+bet[c+5];
        op[(c+6)*NN+n]=(v6-mu)*rs*gam[c+6]+bet[c+6];
        op[(c+7)*NN+n]=(v7-mu)*rs*gam[c+7]+bet[c+7];
    }
}

// --------------------------------- Fused GRU (round-1 version, proven 60.1us).
// 256 threads / 4 waves at __launch_bounds__(256,2): 256-reg unified budget,
// weights live in the VGPR/AGPR file (no spill). waves 0-1: GRU1; 2-3: GRU2.
__global__ __launch_bounds__(256,2) void k_gruf(
    const float* __restrict__ hlng, const u32* __restrict__ wpk,
    const float* __restrict__ bi1, const float* __restrict__ bh1,
    const float* __restrict__ bi2, const float* __restrict__ bh2,
    const float* __restrict__ Wf, const float* __restrict__ bfv,
    void* __restrict__ outp, const int* __restrict__ flag)
{
    const int b=blockIdx.x, t=threadIdx.x;
    const int wave=t>>6, lane=t&63;
    const int layer=wave>>1;        // 0 = GRU1, 1 = GRU2
    const int ublk=wave&1;          // unit block
    const int uu=lane&31, s=lane>>5;
    const int u=ublk*32+uu;         // hidden unit

    __shared__ __align__(16) u32 s_x1[64*16];   // GRU1 input fp16-packed [step][16]
    __shared__ __align__(16) u32 s_h1[2][32];   // h1/y1 double buffer (64 f16)
    __shared__ __align__(16) u32 s_h2[2][32];   // h2 double buffer
    __shared__ float s_h2f[64];

    { const float2* g=(const float2*)(hlng + (size_t)b*2048);
      for(int w=t;w<1024;w+=256){ float2 v=g[w]; s_x1[w]=packf16(v.x,v.y); } }
    if(t<32){ s_h1[0][t]=0u; s_h1[1][t]=0u; s_h2[0][t]=0u; s_h2[1][t]=0u; }

    u32 wiR[16],wiZ[16],wiN[16],whR[16],whZ[16],whN[16];
    const u32* wiu = wpk + (size_t)(layer*2+0)*6144;
    const u32* whu = wpk + (size_t)(layer*2+1)*6144;
    if(layer==0){
        #pragma unroll
        for(int k=0;k<8;k++){
            wiR[k]=wiu[u*32+s*8+k];
            wiZ[k]=wiu[(64+u)*32+s*8+k];
            wiN[k]=wiu[(128+u)*32+s*8+k];
        }
        #pragma unroll
        for(int k=0;k<8;k++){ PIN(wiR[k]); PIN(wiZ[k]); PIN(wiN[k]); }
        #pragma unroll
        for(int k=0;k<16;k++){
            whR[k]=whu[u*32+s*16+k];
            whZ[k]=whu[(64+u)*32+s*16+k];
            whN[k]=whu[(128+u)*32+s*16+k];
        }
        #pragma unroll
        for(int k=0;k<16;k++){ PIN(whR[k]); PIN(whZ[k]); PIN(whN[k]); }
    } else {
        #pragma unroll
        for(int k=0;k<16;k++){
            wiR[k]=wiu[u*32+s*16+k];
            wiZ[k]=wiu[(64+u)*32+s*16+k];
            wiN[k]=wiu[(128+u)*32+s*16+k];
            whR[k]=whu[u*32+s*16+k];
            whZ[k]=whu[(64+u)*32+s*16+k];
            whN[k]=whu[(128+u)*32+s*16+k];
        }
        #pragma unroll
        for(int k=0;k<16;k++){
            PIN(wiR[k]); PIN(wiZ[k]); PIN(wiN[k]);
            PIN(whR[k]); PIN(whZ[k]); PIN(whN[k]);
        }
    }
    const float* bi = layer? bi2:bi1;
    const float* bh = layer? bh2:bh1;
    float br=bi[u]+bh[u], bz=bi[64+u]+bh[64+u], bxn=bi[128+u], bhn=bh[128+u];
    float h=0.f;
    __syncthreads();

    for(int it=0; it<=64; ++it){
        const int pb=(it-1)&1, cb=it&1;
        bool act;
        float pr=0.f,pz=0.f,pxn=0.f,phn=0.f;
        if(layer==0){
            act=(it<64);
            if(act){
                const u32* xp=&s_x1[it*16+s*8];
                const u32* hp=&s_h1[pb][s*16];
                #pragma unroll
                for(int k=0;k<8;k++){ u32 xv=xp[k]; pr=dot2(xv,wiR[k],pr); pz=dot2(xv,wiZ[k],pz); pxn=dot2(xv,wiN[k],pxn); }
                #pragma unroll
                for(int k=0;k<16;k++){ u32 hv=hp[k]; pr=dot2(hv,whR[k],pr); pz=dot2(hv,whZ[k],pz); phn=dot2(hv,whN[k],phn); }
            }
        } else {
            act=(it>=1);
            if(act){
                const u32* xp=&s_h1[pb][s*16];   // y1[it-1]
                const u32* hp=&s_h2[pb][s*16];
                #pragma unroll
                for(int k=0;k<16;k++){
                    u32 xv=xp[k], hv=hp[k];
                    pr=dot2(xv,wiR[k],pr); pz=dot2(xv,wiZ[k],pz); pxn=dot2(xv,wiN[k],pxn);
                    pr=dot2(hv,whR[k],pr); pz=dot2(hv,whZ[k],pz); phn=dot2(hv,whN[k],phn);
                }
            }
        }
        if(act){
            pr  += __shfl_xor(pr ,32,64);
            pz  += __shfl_xor(pz ,32,64);
            pxn += __shfl_xor(pxn,32,64);
            phn += __shfl_xor(phn,32,64);
            float r=sigm(pr+br), z=sigm(pz+bz);
            float n=tanh_(pxn+bxn + r*(phn+bhn));
            h=(1.f-z)*n + z*h;
            if(s==0){
                u16 hv=f2h16(h);
                if(layer==0) ((u16*)s_h1[cb])[u]=hv;
                else { ((u16*)s_h2[cb])[u]=hv; if(it==64) s_h2f[u]=h; }
            }
        }
        __syncthreads();
    }

    if(t<OUT_CH){
        float acc=bfv[t];
        const float4* wp=(const float4*)(Wf + t*64);
        const float4* hp=(const float4*)s_h2f;
        #pragma unroll
        for(int k=0;k<16;k++){
            float4 w=wp[k], v=hp[k];
            acc += w.x*v.x + w.y*v.y + w.z*v.z + w.w*v.w;
        }
        if(*flag) ((float*)outp)[b*OUT_CH+t]=acc;
        else      ((u16*)outp)[b*OUT_CH+t]=f2bf(acc);
    }
}

extern "C" void kernel_launch(void* const* d_in, const int* in_sizes, int n_in,
                              void* d_out, int out_size, void* d_ws, size_t ws_size,
                              hipStream_t stream)
{
    char* ws=(char*)d_ws;
    int* flag = (int*)ws;
    float* cf = (float*)(ws + 256);
    float* c_x   = cf; cf+=196608;
    float* c_W1  = cf; cf+=6144;
    float* c_as1 = cf; cf+=512;
    float* c_ad1 = cf; cf+=512;
    float* c_b1  = cf; cf+=512;
    float* c_as2 = cf; cf+=64;
    float* c_ad2 = cf; cf+=64;
    float* c_b2  = cf; cf+=64;
    float* c_gam = cf; cf+=64;
    float* c_bet = cf; cf+=64;
    float* c_bi1 = cf; cf+=192;
    float* c_bh1 = cf; cf+=192;
    float* c_bi2 = cf; cf+=192;
    float* c_bh2 = cf; cf+=192;
    float* c_Wf  = cf; cf+=576;
    float* c_bf  = cf; cf+=9;
    uintptr_t p = ((uintptr_t)cf + 255) & ~(uintptr_t)255;
    u16* c_W2i = (u16*)p;                        // 32768 f16 = 64 KB (interleaved)
    p = (p + 32768*2 + 255) & ~(uintptr_t)255;
    u32* wpk = (u32*)p;                          // 4*192*32 u32 = 96 KB (packed GRU weights)
    p = (p + 24576*4 + 255) & ~(uintptr_t)255;
    float* hlng = (float*)p;                     // 512*64*32 f32 = 4.19 MB

    const int* ei = (const int*)d_in[1];

    CvtDesc d;
    const int srcIdx[16] = {0,2,3,4,5,7,8,9,10,11,14,15,18,19,20,21};
    void* dsts[16] = {c_x,c_W1,c_as1,c_ad1,c_b1,c_as2,c_ad2,c_b2,c_gam,c_bet,
                      c_bi1,c_bh1,c_bi2,c_bh2,c_Wf,c_bf};
    const int ns[16] = {196608,6144,512,512,512,64,64,64,64,64,
                        192,192,192,192,576,9};
    for(int i=0;i<16;i++){ d.src[i]=d_in[srcIdx[i]]; d.dst[i]=dsts[i]; d.n[i]=ns[i]; }

    k_setup <<<dim3(352),dim3(256),0,stream>>>((const u32*)d_in[0], d,
                                               d_in[6], c_W2i,
                                               d_in[12], d_in[13], d_in[16], d_in[17],
                                               wpk, flag);
    k_ab    <<<dim3(BATCH),dim3(512),0,stream>>>(
        c_x, ei, c_W1, c_as1, c_ad1, c_b1,
        (const uint4*)c_W2i, c_as2, c_ad2, c_b2, c_gam, c_bet, hlng);
    k_gruf  <<<dim3(BATCH),dim3(256),0,stream>>>(hlng, wpk, c_bi1,c_bh1,c_bi2,c_bh2,
                                                 c_Wf, c_bf, d_out, flag);
}